// Round 2
// baseline (35.991 us; speedup 1.0000x reference)
//
#include <hip/hip_runtime.h>

// CountHistogram: B=128, C=4, Q=32, D=2048, NBINS=30
// out[b,c,q,bin] = sum_d [ bin(simmat[b,c,q,d]) == bin ] * (dtoks[b,d]!=-1) * (qtoks[b,q]!=-1)
//
// Design (R1): one wave per (b,c,q) row, no __syncthreads.
//   - pre-kernel packs (dtoks != -1) into bitmask: masks[b][64] u32, word w covers elems 32w..32w+31
//   - main kernel: wave loads 8 float4/lane (32 elems), tests mask nibble, LDS atomic per-wave histogram.

#define NBINS 30
#define DIM   2048
#define QDIM  32
#define CDIM  4
#define BDIM  128

__global__ __launch_bounds__(64) void make_mask_kernel(
    const int* __restrict__ dtoks, unsigned int* __restrict__ masks)
{
    const int b    = blockIdx.x;
    const int lane = threadIdx.x;
    #pragma unroll
    for (int w = 0; w < 32; ++w) {
        const int t = dtoks[b * DIM + w * 64 + lane];
        const unsigned long long m = __ballot(t != -1);
        if (lane == 0) {
            masks[b * 64 + 2 * w]     = (unsigned int)(m & 0xffffffffu);
            masks[b * 64 + 2 * w + 1] = (unsigned int)(m >> 32);
        }
    }
}

__global__ __launch_bounds__(256) void CountHistogram_kernel(
    const float*        __restrict__ simmat,
    const unsigned int* __restrict__ masks,
    const int*          __restrict__ qtoks,
    float*              __restrict__ out)
{
    const int tid  = threadIdx.x;
    const int wave = tid >> 6;
    const int lane = tid & 63;
    const int row  = blockIdx.x * 4 + wave;          // = b*C*Q + c*Q + q
    const int q    = row & (QDIM - 1);
    const int b    = row >> 7;                       // / (C*Q)

    __shared__ int h[4][32];                         // per-wave private histogram
    if (lane < 32) h[wave][lane] = 0;                // DS ops within a wave are in-order

    const int qt = qtoks[b * QDIM + q];              // wave-uniform

    if (qt != -1) {
        const float4* sm = (const float4*)(simmat + (size_t)row * DIM);
        const unsigned int* mk = masks + b * 64;
        #pragma unroll
        for (int j = 0; j < 8; ++j) {
            // float4 index j*64+lane covers elements 4*(j*64+lane) .. +3
            const float4 s = sm[j * 64 + lane];
            // mask nibble: word (j*8 + lane/8), bits 4*(lane&7)..+3
            const unsigned int mw  = mk[j * 8 + (lane >> 3)];
            const unsigned int nib = (mw >> (4 * (lane & 7))) & 0xF;
            // bit-exact replication of ((x + 1.00001f) / 2.0f) * 29.0f, trunc-to-int
            int b0 = (int)((s.x + 1.00001f) / 2.0f * 29.0f);
            int b1 = (int)((s.y + 1.00001f) / 2.0f * 29.0f);
            int b2 = (int)((s.z + 1.00001f) / 2.0f * 29.0f);
            int b3 = (int)((s.w + 1.00001f) / 2.0f * 29.0f);
            if (nib & 1u) atomicAdd(&h[wave][b0], 1);
            if (nib & 2u) atomicAdd(&h[wave][b1], 1);
            if (nib & 4u) atomicAdd(&h[wave][b2], 1);
            if (nib & 8u) atomicAdd(&h[wave][b3], 1);
        }
    }

    // same-wave DS ordering guarantees atomics above complete before this read
    if (lane < NBINS) {
        out[(size_t)row * NBINS + lane] = (float)h[wave][lane];
    }
}

extern "C" void kernel_launch(void* const* d_in, const int* in_sizes, int n_in,
                              void* d_out, int out_size, void* d_ws, size_t ws_size,
                              hipStream_t stream) {
    const float* simmat = (const float*)d_in[0];
    // d_in[1] = dlens (unused by the reference)
    const int*   dtoks  = (const int*)d_in[2];
    const int*   qtoks  = (const int*)d_in[3];
    float*       out    = (float*)d_out;
    unsigned int* masks = (unsigned int*)d_ws;       // 128*64*4 = 32 KB

    make_mask_kernel<<<BDIM, 64, 0, stream>>>(dtoks, masks);

    const int nrows = BDIM * CDIM * QDIM;            // 16384
    CountHistogram_kernel<<<nrows / 4, 256, 0, stream>>>(simmat, masks, qtoks, out);
}

// Round 3
// 28.281 us; speedup vs baseline: 1.2726x; 1.2726x over previous
//
#include <hip/hip_runtime.h>

// CountHistogram: B=128, C=4, Q=32, D=2048, NBINS=30
// out[b,c,q,bin] = sum_d [ bin(simmat[b,c,q,d]) == bin ] * (dtoks[b,d]!=-1) * (qtoks[b,q]!=-1)
//
// Design (R2): fused, one wave per row, no barriers.
//   - per-wave histogram split into 4 bank-rotated 16-lane-group copies:
//     group g (lane>>4) increments hs[wave][g][(bin + 8g) & 31]
//     -> same bin across groups = different banks; conflicts limited to 16 lanes.

#define NBINS 30
#define DIM   2048
#define QDIM  32
#define CDIM  4
#define BDIM  128

__global__ __launch_bounds__(256) void CountHistogram_kernel(
    const float* __restrict__ simmat,
    const int*   __restrict__ dtoks,
    const int*   __restrict__ qtoks,
    float*       __restrict__ out)
{
    const int tid  = threadIdx.x;
    const int wave = tid >> 6;
    const int lane = tid & 63;
    const int row  = blockIdx.x * 4 + wave;          // = b*C*Q + c*Q + q
    const int q    = row & (QDIM - 1);
    const int b    = row >> 7;                       // / (C*Q)

    __shared__ int hs[4][4][32];                     // [wave][group][rotated bin]
    int* hw = &hs[wave][0][0];
    hw[lane]      = 0;                               // 128 words per wave, 2 per lane
    hw[lane + 64] = 0;

    const int qt   = qtoks[b * QDIM + q];            // wave-uniform
    const int rotg = (lane & 48) >> 1;               // 8 * (lane>>4)
    int* hg = &hs[wave][lane >> 4][0];

    if (qt != -1) {
        const float4* sm = (const float4*)(simmat + (size_t)row * DIM);
        const int4*   dt = (const int4*)(dtoks  + (size_t)b   * DIM);
        #pragma unroll
        for (int j = 0; j < 8; ++j) {
            const float4 s = sm[j * 64 + lane];
            const int4   t = dt[j * 64 + lane];
            // bit-exact replication of ((x + 1.00001f) / 2.0f) * 29.0f, trunc-to-int
            int b0 = (int)((s.x + 1.00001f) / 2.0f * 29.0f);
            int b1 = (int)((s.y + 1.00001f) / 2.0f * 29.0f);
            int b2 = (int)((s.z + 1.00001f) / 2.0f * 29.0f);
            int b3 = (int)((s.w + 1.00001f) / 2.0f * 29.0f);
            if (t.x != -1) atomicAdd(&hg[(b0 + rotg) & 31], 1);
            if (t.y != -1) atomicAdd(&hg[(b1 + rotg) & 31], 1);
            if (t.z != -1) atomicAdd(&hg[(b2 + rotg) & 31], 1);
            if (t.w != -1) atomicAdd(&hg[(b3 + rotg) & 31], 1);
        }
    }

    // same-wave DS ordering: atomics above complete before these reads
    if (lane < NBINS) {
        int sum = 0;
        #pragma unroll
        for (int g = 0; g < 4; ++g)
            sum += hs[wave][g][(lane + 8 * g) & 31];
        out[(size_t)row * NBINS + lane] = (float)sum;
    }
}

extern "C" void kernel_launch(void* const* d_in, const int* in_sizes, int n_in,
                              void* d_out, int out_size, void* d_ws, size_t ws_size,
                              hipStream_t stream) {
    const float* simmat = (const float*)d_in[0];
    // d_in[1] = dlens (unused by the reference)
    const int*   dtoks  = (const int*)d_in[2];
    const int*   qtoks  = (const int*)d_in[3];
    float*       out    = (float*)d_out;

    const int nrows = BDIM * CDIM * QDIM;            // 16384
    CountHistogram_kernel<<<nrows / 4, 256, 0, stream>>>(simmat, dtoks, qtoks, out);
}

// Round 5
// 27.542 us; speedup vs baseline: 1.3067x; 1.0268x over previous
//
#include <hip/hip_runtime.h>

// CountHistogram: B=128, C=4, Q=32, D=2048, NBINS=30
// out[b,c,q,bin] = sum_d [ bin(simmat[b,c,q,d]) == bin ] * (dtoks[b,d]!=-1) * (qtoks[b,q]!=-1)
//
// Design (R4 = R3 with compile fix): fused, one wave per row, no barriers.
//   - 8 sub-histograms per wave (one per 8-lane group), stride 33 words:
//     bank(bin, group g) = (33g + bin) mod 32 = (g + bin) mod 32
//     -> same bin across the 8 groups = 8 consecutive banks (conflict-free),
//        same-address collisions confined to 8 lanes.
//   - masked elements redirected to dead slot 31 (cndmask) -> unconditional
//     ds_add, no exec-mask churn.
//   - nontemporal loads for the simmat stream (read-once) via ext_vector_type
//     (the builtin rejects HIP_vector_type float4).

#define NBINS  30
#define DIM    2048
#define QDIM   32
#define CDIM   4
#define BDIM   128
#define GSTRIDE 33                                  // words per group histogram
#define WSTRIDE (8 * GSTRIDE)                       // 264 words per wave

typedef float nfloat4 __attribute__((ext_vector_type(4)));
typedef int   nint4   __attribute__((ext_vector_type(4)));

__global__ __launch_bounds__(256) void CountHistogram_kernel(
    const float* __restrict__ simmat,
    const int*   __restrict__ dtoks,
    const int*   __restrict__ qtoks,
    float*       __restrict__ out)
{
    const int tid  = threadIdx.x;
    const int wave = tid >> 6;
    const int lane = tid & 63;
    const int row  = blockIdx.x * 4 + wave;          // = b*C*Q + c*Q + q
    const int q    = row & (QDIM - 1);
    const int b    = row >> 7;                       // / (C*Q)

    __shared__ int hs[4 * WSTRIDE];                  // 4 waves * 8 groups * 33 words
    int* hw = hs + wave * WSTRIDE;
    // zero 264 words per wave (DS ops within a wave are in-order w.r.t. later atomics)
    hw[lane] = 0; hw[lane + 64] = 0; hw[lane + 128] = 0; hw[lane + 192] = 0;
    if (lane < WSTRIDE - 256) hw[lane + 256] = 0;

    const int qt = qtoks[b * QDIM + q];              // wave-uniform
    int* hg = hw + (lane >> 3) * GSTRIDE;            // this lane's group histogram

    if (qt != -1) {
        const nfloat4* sm = (const nfloat4*)(simmat + (size_t)row * DIM);
        const nint4*   dt = (const nint4*)(dtoks  + (size_t)b   * DIM);
        #pragma unroll
        for (int j = 0; j < 8; ++j) {
            const nfloat4 s = __builtin_nontemporal_load(&sm[j * 64 + lane]);
            const nint4   t = dt[j * 64 + lane];
            // bit-exact replication of ((x + 1.00001f) / 2.0f) * 29.0f, trunc-to-int
            int b0 = (int)((s.x + 1.00001f) / 2.0f * 29.0f);
            int b1 = (int)((s.y + 1.00001f) / 2.0f * 29.0f);
            int b2 = (int)((s.z + 1.00001f) / 2.0f * 29.0f);
            int b3 = (int)((s.w + 1.00001f) / 2.0f * 29.0f);
            // masked elements -> dead slot 31 (bins 30..32 never read back)
            b0 = (t.x != -1) ? b0 : 31;
            b1 = (t.y != -1) ? b1 : 31;
            b2 = (t.z != -1) ? b2 : 31;
            b3 = (t.w != -1) ? b3 : 31;
            atomicAdd(&hg[b0], 1);
            atomicAdd(&hg[b1], 1);
            atomicAdd(&hg[b2], 1);
            atomicAdd(&hg[b3], 1);
        }
    }

    // same-wave DS ordering: atomics above complete before these reads
    if (lane < NBINS) {
        int sum = 0;
        #pragma unroll
        for (int g = 0; g < 8; ++g)
            sum += hw[g * GSTRIDE + lane];
        out[(size_t)row * NBINS + lane] = (float)sum;
    }
}

extern "C" void kernel_launch(void* const* d_in, const int* in_sizes, int n_in,
                              void* d_out, int out_size, void* d_ws, size_t ws_size,
                              hipStream_t stream) {
    const float* simmat = (const float*)d_in[0];
    // d_in[1] = dlens (unused by the reference)
    const int*   dtoks  = (const int*)d_in[2];
    const int*   qtoks  = (const int*)d_in[3];
    float*       out    = (float*)d_out;

    const int nrows = BDIM * CDIM * QDIM;            // 16384
    CountHistogram_kernel<<<nrows / 4, 256, 0, stream>>>(simmat, dtoks, qtoks, out);
}